// Round 6
// baseline (123.612 us; speedup 1.0000x reference)
//
#include <hip/hip_runtime.h>
#include <hip/hip_fp16.h>

typedef _Float16 f16x8 __attribute__((ext_vector_type(8)));
typedef _Float16 f16x4 __attribute__((ext_vector_type(4)));
typedef _Float16 f16x2 __attribute__((ext_vector_type(2)));
typedef float f32x4 __attribute__((ext_vector_type(4)));

// Workspace layout (bytes):
//   qv     [0,       65536)   : 32x512 f32   q = query @ Wq^T
//   bfrag  [65536,   589824)  : 512x512 f16  Wk^T in MFMA-fragment-major layout
//   scores [589824,  851968)  : 32x2048 f32  pre-softmax scores
//   vpart  [851968, 2949120)  : 2048x512 f16 per-tile unnormalized attn@keys
//   stats  [2949120, 2965504) : 2048x2 f32   per-tile (m, l)
#define WS_QV 0
#define WS_BF 65536
#define WS_SC 589824
#define WS_VP 851968
#define WS_ST 2949120

// ---------------- P: qv = query@Wq^T (fp32) + prepack Wk -> fp16 fragment layout ----
__global__ __launch_bounds__(256) void prep_kernel(
    const float* __restrict__ query, const float* __restrict__ Wq,
    const float* __restrict__ Wk, float* __restrict__ qv,
    _Float16* __restrict__ bfrag) {
  const int blk = blockIdx.x, tid = threadIdx.x;
  if (blk < 64) {
    const int b = blk >> 1;
    const int h = ((blk & 1) << 8) + tid;
    const float4* qr = (const float4*)(query + (size_t)b * 512);
    const float4* wr = (const float4*)(Wq + (size_t)h * 512);
    float acc = 0.f;
#pragma unroll 8
    for (int i = 0; i < 128; ++i) {
      float4 a = qr[i], w = wr[i];
      acc += a.x * w.x + a.y * w.y + a.z * w.z + a.w * w.w;
    }
    qv[b * 512 + h] = acc;
  } else {
    // B-fragment for mfma_f32_16x16x32_f16: unit u = nt*16 + ks
    // lane l supplies B[k = 32*ks + 8*(l>>4)+e][col = 16*nt + (l&15)] = Wk[col][k]
    const int u = (blk - 64) * 4 + (tid >> 6);
    const int l = tid & 63;
    const int col = ((u >> 4) << 4) + (l & 15);
    const int k0 = ((u & 15) << 5) + ((l >> 4) << 3);
    const float4* src = (const float4*)(Wk + (size_t)col * 512 + k0);
    float4 x = src[0], y = src[1];
    f16x8 v;
    v[0] = (_Float16)x.x; v[1] = (_Float16)x.y;
    v[2] = (_Float16)x.z; v[3] = (_Float16)x.w;
    v[4] = (_Float16)y.x; v[5] = (_Float16)y.y;
    v[6] = (_Float16)y.z; v[7] = (_Float16)y.w;
    *(f16x8*)(bfrag + (size_t)u * 512 + l * 8) = v;
  }
}

// ---------------- F: fused keys@Wk^T -> tanh -> scores -> tile softmax -> attn@keys
// Grid 2048: wg = 32 rows. 4 waves; wave w owns h-cols [128w, 128w+128).
// BARRIER-FREE main loop: each wave has a private 2x4KB LDS double-buffer and
// stages its own 32x64 keys chunk (8 chunks of k=64), starting at chunk 2w+2
// (rotated) so waves de-phase and finish holding chunks {2w,2w+1} = the k-slice
// [128w,128w+128) the wave later needs for the V-phase (V read from own LDS).
__global__ __launch_bounds__(256) void fused_kernel(
    const float* __restrict__ keys, const _Float16* __restrict__ bfrag,
    const float* __restrict__ qv, const float* __restrict__ w_att,
    float* __restrict__ scores, _Float16* __restrict__ vpart,
    float* __restrict__ stats) {
  __shared__ __align__(128) unsigned char lds[32768];   // 4 waves x 2 x 4KB
  __shared__ float spart[128];
  __shared__ float pb[32];
  __shared__ float pb2[32];
  const int tid = threadIdx.x, w = tid >> 6, l = tid & 63;
  const int wg = blockIdx.x;
  const int row0 = wg * 32;
  const int b = row0 >> 11;

  unsigned char* mybuf = lds + w * 8192;       // wave-private

  // staging: lane covers rows (l>>4)+4j (j=0..7), 4 consecutive f32 at col (l&15)*4
  const int srow = l >> 4;
  const int scol4 = (l & 15) << 2;
  const float* gbase = keys + (size_t)(row0 + srow) * 512 + scol4;
  const int wbyte = scol4 << 1;                // 8B per f16x4

  float4 stg[8];
  const int cs0 = (2 * w + 2) & 7;
#pragma unroll
  for (int j = 0; j < 8; ++j)
    stg[j] = *(const float4*)(gbase + (size_t)(4 * j) * 512 + cs0 * 64);
  {
    unsigned char* bb = mybuf;                 // parity 0
#pragma unroll
    for (int j = 0; j < 8; ++j) {
      const int r = srow + 4 * j;
      f16x4 h;
      h[0] = (_Float16)stg[j].x; h[1] = (_Float16)stg[j].y;
      h[2] = (_Float16)stg[j].z; h[3] = (_Float16)stg[j].w;
      *(f16x4*)(bb + r * 128 + (wbyte ^ ((r & 7) << 4))) = h;
    }
  }

  f32x4 acc[2][8];
#pragma unroll
  for (int mt = 0; mt < 2; ++mt)
#pragma unroll
    for (int nt = 0; nt < 8; ++nt) {
      acc[mt][nt][0] = 0.f; acc[mt][nt][1] = 0.f;
      acc[mt][nt][2] = 0.f; acc[mt][nt][3] = 0.f;
    }

  const int aswz = (l & 7) << 4;
  const int akslot = (l >> 4) << 4;            // 16B k-slot within 128B row

#pragma unroll
  for (int i = 0; i < 8; ++i) {
    // ---- issue global loads for chunk i+1 (in flight during compute)
    const int csn = (2 * w + 3 + i) & 7;
    if (i < 7) {
#pragma unroll
      for (int j = 0; j < 8; ++j)
        stg[j] = *(const float4*)(gbase + (size_t)(4 * j) * 512 + csn * 64);
    }
    __builtin_amdgcn_sched_barrier(0);

    // ---- compute chunk i from private buf[i&1]
    const unsigned char* bb = mybuf + (i & 1) * 4096;
    const int csc = (2 * w + 2 + i) & 7;
#pragma unroll
    for (int ks = 0; ks < 2; ++ks) {
      const int KS = csc * 2 + ks;
      f16x8 af[2];
#pragma unroll
      for (int mt = 0; mt < 2; ++mt) {
        const int r = (mt << 4) + (l & 15);
        af[mt] = *(const f16x8*)(bb + r * 128 + ((ks * 64 + akslot) ^ aswz));
      }
#pragma unroll
      for (int nh = 0; nh < 2; ++nh) {
        f16x8 bf[4];
#pragma unroll
        for (int n4 = 0; n4 < 4; ++n4) {
          int u = (w * 8 + nh * 4 + n4) * 16 + KS;
          bf[n4] = *(const f16x8*)(bfrag + (size_t)u * 512 + l * 8);
        }
#pragma unroll
        for (int mt = 0; mt < 2; ++mt)
#pragma unroll
          for (int n4 = 0; n4 < 4; ++n4)
            acc[mt][nh * 4 + n4] = __builtin_amdgcn_mfma_f32_16x16x32_f16(
                af[mt], bf[n4], acc[mt][nh * 4 + n4], 0, 0, 0);
      }
    }
    __builtin_amdgcn_sched_barrier(0);

    // ---- cvt + write chunk i+1 into private buf[(i+1)&1]  (same-wave order)
    if (i < 7) {
      unsigned char* db = mybuf + ((i + 1) & 1) * 4096;
#pragma unroll
      for (int j = 0; j < 8; ++j) {
        const int r = srow + 4 * j;
        f16x4 h;
        h[0] = (_Float16)stg[j].x; h[1] = (_Float16)stg[j].y;
        h[2] = (_Float16)stg[j].z; h[3] = (_Float16)stg[j].w;
        *(f16x4*)(db + r * 128 + (wbyte ^ ((r & 7) << 4))) = h;
      }
    }
  }
  // buffers now hold: buf0 = chunk 2w (k [128w,128w+64)), buf1 = chunk 2w+1.

  // ---- epilogue: tanh(qv + k) * w_att, reduce over h -> per-row scores
  float rs[8];
#pragma unroll
  for (int i = 0; i < 8; ++i) rs[i] = 0.f;
  const int hb = w * 128;
#pragma unroll
  for (int nt = 0; nt < 8; ++nt) {
    const int h = hb + nt * 16 + (l & 15);
    const float q = qv[b * 512 + h];
    const float wa = w_att[h];
#pragma unroll
    for (int mt = 0; mt < 2; ++mt)
#pragma unroll
      for (int r = 0; r < 4; ++r) {
        float x = q + acc[mt][nt][r];
        float e = __expf(x + x);
        float t = 1.f - __fdividef(2.f, e + 1.f);
        rs[mt * 4 + r] = __builtin_fmaf(t, wa, rs[mt * 4 + r]);
      }
  }
#pragma unroll
  for (int st = 1; st <= 8; st <<= 1)
#pragma unroll
    for (int i = 0; i < 8; ++i)
      rs[i] += __shfl_xor(rs[i], st, 64);

  {
    const int idx = l & 15;     // lanes 0..7 of each col-group write
    if (idx < 8) {
      float v = rs[0];
#pragma unroll
      for (int i = 1; i < 8; ++i) v = (idx == i) ? rs[i] : v;
      // row for (mt=idx>>2, r=idx&3): 16*mt + 4*(l>>4) + r
      const int rrow = ((idx >> 2) << 4) + ((l >> 4) << 2) + (idx & 3);
      spart[w * 32 + rrow] = v;
    }
  }
  __syncthreads();
  if (tid < 32) {
    float s = spart[tid] + spart[32 + tid] + spart[64 + tid] + spart[96 + tid];
    scores[row0 + tid] = s;
    pb[tid] = s;
  }
  __syncthreads();

  // ---- tile softmax stats
  float m = -1e30f;
#pragma unroll 8
  for (int r = 0; r < 32; ++r) m = fmaxf(m, pb[r]);      // broadcast reads
  if (tid < 32) pb2[tid] = __expf(pb[tid] - m);
  __syncthreads();

  // ---- V-partial from own LDS k-slice: wave w owns d in [128w, 128w+128)
  // lane l: d = 128w + 2l; buf = l>>5 (chunk 2w or 2w+1), col byte (l&31)*4
  {
    const unsigned char* vb = mybuf + (l >> 5) * 4096;
    const int vcol = (l & 31) << 2;
    float a0 = 0.f, a1 = 0.f;
#pragma unroll 8
    for (int r = 0; r < 32; ++r) {
      f16x2 kv = *(const f16x2*)(vb + r * 128 + (vcol ^ ((r & 7) << 4)));
      float p = pb2[r];
      a0 = __builtin_fmaf(p, (float)kv[0], a0);
      a1 = __builtin_fmaf(p, (float)kv[1], a1);
    }
    f16x2 o;
    o[0] = (_Float16)a0;
    o[1] = (_Float16)a1;
    *(f16x2*)(vpart + (size_t)wg * 512 + w * 128 + 2 * l) = o;
  }
  if (tid == 0) {
    float lsum = 0.f;
#pragma unroll 8
    for (int r = 0; r < 32; ++r) lsum += pb2[r];
    stats[wg * 2] = m;
    stats[wg * 2 + 1] = lsum;
  }
}

// ---------------- C: combine 64 tiles per batch -> out, attn ----------------------
__global__ __launch_bounds__(256) void combine_kernel(
    const _Float16* __restrict__ vpart, const float* __restrict__ stats,
    const float* __restrict__ scores, float* __restrict__ out,
    float* __restrict__ attn) {
  __shared__ float smt[64], slt[64];
  const int blk = blockIdx.x, tid = threadIdx.x;
  const int b = blk & 31;
  if (tid < 64) {
    smt[tid] = stats[(b * 64 + tid) * 2];
    slt[tid] = stats[(b * 64 + tid) * 2 + 1];
  }
  __syncthreads();
  float M = -1e30f;
#pragma unroll 8
  for (int t = 0; t < 64; ++t) M = fmaxf(M, smt[t]);     // broadcast reads
  float L = 0.f;
#pragma unroll 8
  for (int t = 0; t < 64; ++t) L += __expf(smt[t] - M) * slt[t];
  const float rinv = 1.f / L;

  if (blk < 32) {
    const int d0 = 2 * tid;
    float a0 = 0.f, a1 = 0.f;
#pragma unroll 8
    for (int t = 0; t < 64; ++t) {
      float wgt = __expf(smt[t] - M);
      f16x2 vp = *(const f16x2*)(vpart + ((size_t)(b * 64 + t)) * 512 + d0);
      a0 = __builtin_fmaf(wgt, (float)vp[0], a0);
      a1 = __builtin_fmaf(wgt, (float)vp[1], a1);
    }
    out[b * 512 + d0] = a0 * rinv;
    out[b * 512 + d0 + 1] = a1 * rinv;
  } else {
#pragma unroll
    for (int j = 0; j < 8; ++j) {
      int s = j * 256 + tid;
      attn[(size_t)b * 2048 + s] = __expf(scores[(size_t)b * 2048 + s] - M) * rinv;
    }
  }
}

extern "C" void kernel_launch(void* const* d_in, const int* in_sizes, int n_in,
                              void* d_out, int out_size, void* d_ws, size_t ws_size,
                              hipStream_t stream) {
  const float* query = (const float*)d_in[0];
  const float* keys  = (const float*)d_in[1];
  const float* Wq    = (const float*)d_in[2];
  const float* Wk    = (const float*)d_in[3];
  const float* w_att = (const float*)d_in[4];
  float* out  = (float*)d_out;                  // [32,512]
  float* attn = out + 16384;                    // [32,2048]
  char* ws = (char*)d_ws;
  float*    qv     = (float*)(ws + WS_QV);
  _Float16* bfrag  = (_Float16*)(ws + WS_BF);
  float*    scores = (float*)(ws + WS_SC);
  _Float16* vpart  = (_Float16*)(ws + WS_VP);
  float*    stats  = (float*)(ws + WS_ST);

  prep_kernel<<<192, 256, 0, stream>>>(query, Wq, Wk, qv, bfrag);
  fused_kernel<<<2048, 256, 0, stream>>>(keys, bfrag, qv, w_att, scores, vpart, stats);
  combine_kernel<<<64, 256, 0, stream>>>(vpart, stats, scores, out, attn);
}

// Round 7
// 113.648 us; speedup vs baseline: 1.0877x; 1.0877x over previous
//
#include <hip/hip_runtime.h>
#include <hip/hip_fp16.h>

typedef _Float16 f16x8 __attribute__((ext_vector_type(8)));
typedef _Float16 f16x4 __attribute__((ext_vector_type(4)));
typedef float f32x4 __attribute__((ext_vector_type(4)));

// Workspace layout (bytes):
//   qv     [0,       65536)   : 32x512 f32   q = query @ Wq^T
//   bfrag  [65536,   589824)  : 512x512 f16  Wk^T in MFMA-fragment-major layout
//   spart  [589824,  1114112) : 2x32x2048 f32 partial scores (h-half 0, 1)
//   vpart  [1114112, 2162688) : 1024x512 f16  per-(b,sc) normalized attn@keys
#define WS_QV 0
#define WS_BF 65536
#define WS_SP 589824
#define WS_VP 1114112

// ---------------- P: qv = query@Wq^T (fp32) + prepack Wk -> fp16 fragment layout ----
__global__ __launch_bounds__(256) void prep_kernel(
    const float* __restrict__ query, const float* __restrict__ Wq,
    const float* __restrict__ Wk, float* __restrict__ qv,
    _Float16* __restrict__ bfrag) {
  const int blk = blockIdx.x, tid = threadIdx.x;
  if (blk < 64) {
    const int b = blk >> 1;
    const int h = ((blk & 1) << 8) + tid;
    const float4* qr = (const float4*)(query + (size_t)b * 512);
    const float4* wr = (const float4*)(Wq + (size_t)h * 512);
    float acc = 0.f;
#pragma unroll 8
    for (int i = 0; i < 128; ++i) {
      float4 a = qr[i], w = wr[i];
      acc += a.x * w.x + a.y * w.y + a.z * w.z + a.w * w.w;
    }
    qv[b * 512 + h] = acc;
  } else {
    // B-fragment for mfma_f32_16x16x32_f16: unit u = nt*16 + ks
    // lane l supplies B[k = 32*ks + 8*(l>>4)+e][col = 16*nt + (l&15)] = Wk[col][k]
    const int u = (blk - 64) * 4 + (tid >> 6);
    const int l = tid & 63;
    const int col = ((u >> 4) << 4) + (l & 15);
    const int k0 = ((u & 15) << 5) + ((l >> 4) << 3);
    const float4* src = (const float4*)(Wk + (size_t)col * 512 + k0);
    float4 x = src[0], y = src[1];
    f16x8 v;
    v[0] = (_Float16)x.x; v[1] = (_Float16)x.y;
    v[2] = (_Float16)x.z; v[3] = (_Float16)x.w;
    v[4] = (_Float16)y.x; v[5] = (_Float16)y.y;
    v[6] = (_Float16)y.z; v[7] = (_Float16)y.w;
    *(f16x8*)(bfrag + (size_t)u * 512 + l * 8) = v;
  }
}

// ---------------- G: partial scores GEMM. Grid 2048 = (row-tile rt) x (h-half hs).
// 512 threads / 8 waves; block tile 64 rows x 256 h; wave (wm,wn) = 32 rows x 64 h.
// acc[2][4] = 32 regs -> total <=128 (launch_bounds 512,4) -> 16 waves/CU.
// Writes spart[hs][row] = sum_{h in half} tanh(qv+k)*w_att.
__global__ __launch_bounds__(512, 4) void gemm_kernel(
    const float* __restrict__ keys, const _Float16* __restrict__ bfrag,
    const float* __restrict__ qv, const float* __restrict__ w_att,
    float* __restrict__ spart_out) {
  __shared__ __align__(128) unsigned char lds[16384];   // 2 x (64 rows x 64 k fp16)
  __shared__ float sred[256];                           // 8 waves x 32 rows
  const int tid = threadIdx.x, w = tid >> 6, l = tid & 63;
  // XCD-chunked bijective map (2048 = 8 x 256): both h-halves of rt on one XCD.
  const int bid = ((blockIdx.x & 7) << 8) + (blockIdx.x >> 3);
  const int rt = bid >> 1, hs = bid & 1;
  const int row0 = rt * 64;
  const int b = row0 >> 11;
  const int wm = w >> 2, wn = w & 3;

  // staging: thread -> row sr, 8 f32 at chunk-local col sc8
  const int sr = tid >> 3, sc8 = (tid & 7) << 3;
  const float* gsrc = keys + (size_t)(row0 + sr) * 512 + sc8;
  const int wbyte = sr * 128 + (sc8 << 1);
  const int wswz = (sr & 7) << 4;

  float4 stg[2];
  stg[0] = ((const float4*)gsrc)[0];
  stg[1] = ((const float4*)gsrc)[1];
  {
    f16x8 h;
    h[0] = (_Float16)stg[0].x; h[1] = (_Float16)stg[0].y;
    h[2] = (_Float16)stg[0].z; h[3] = (_Float16)stg[0].w;
    h[4] = (_Float16)stg[1].x; h[5] = (_Float16)stg[1].y;
    h[6] = (_Float16)stg[1].z; h[7] = (_Float16)stg[1].w;
    *(f16x8*)(lds + (wbyte ^ wswz)) = h;
  }
  __syncthreads();

  f32x4 acc[2][4];
#pragma unroll
  for (int mt = 0; mt < 2; ++mt)
#pragma unroll
    for (int nt = 0; nt < 4; ++nt) {
      acc[mt][nt][0] = 0.f; acc[mt][nt][1] = 0.f;
      acc[mt][nt][2] = 0.f; acc[mt][nt][3] = 0.f;
    }

  const int aswz = (l & 7) << 4;
  const int akslot = (l >> 4) << 4;
  const int arow = (wm * 32 + (l & 15)) * 128;   // + mt*16*128

#pragma unroll
  for (int c = 0; c < 8; ++c) {
    // ---- issue global loads for chunk c+1
    if (c < 7) {
      const float4* g = (const float4*)(gsrc + (c + 1) * 64);
      stg[0] = g[0]; stg[1] = g[1];
    }
    __builtin_amdgcn_sched_barrier(0);

    // ---- compute chunk c from buf[c&1]
    const unsigned char* buf = lds + (c & 1) * 8192;
#pragma unroll
    for (int ks = 0; ks < 2; ++ks) {
      const int KS = c * 2 + ks;
      f16x8 af[2];
#pragma unroll
      for (int mt = 0; mt < 2; ++mt)
        af[mt] = *(const f16x8*)(buf + arow + mt * 2048 +
                                 ((ks * 64 + akslot) ^ aswz));
#pragma unroll
      for (int ng = 0; ng < 2; ++ng) {
        f16x8 bf[2];
#pragma unroll
        for (int n2 = 0; n2 < 2; ++n2) {
          const int u = ((hs << 4) + (wn << 2) + ng * 2 + n2) * 16 + KS;
          bf[n2] = *(const f16x8*)(bfrag + (size_t)u * 512 + l * 8);
        }
#pragma unroll
        for (int mt = 0; mt < 2; ++mt)
#pragma unroll
          for (int n2 = 0; n2 < 2; ++n2)
            acc[mt][ng * 2 + n2] = __builtin_amdgcn_mfma_f32_16x16x32_f16(
                af[mt], bf[n2], acc[mt][ng * 2 + n2], 0, 0, 0);
      }
    }
    __builtin_amdgcn_sched_barrier(0);

    // ---- cvt + write chunk c+1
    if (c < 7) {
      unsigned char* db = lds + ((c + 1) & 1) * 8192;
      f16x8 h;
      h[0] = (_Float16)stg[0].x; h[1] = (_Float16)stg[0].y;
      h[2] = (_Float16)stg[0].z; h[3] = (_Float16)stg[0].w;
      h[4] = (_Float16)stg[1].x; h[5] = (_Float16)stg[1].y;
      h[6] = (_Float16)stg[1].z; h[7] = (_Float16)stg[1].w;
      *(f16x8*)(db + (wbyte ^ wswz)) = h;
    }
    __syncthreads();
  }

  // ---- epilogue: partial sum over this block's 256 h-cols
  float rs[8];
#pragma unroll
  for (int i = 0; i < 8; ++i) rs[i] = 0.f;
#pragma unroll
  for (int nt = 0; nt < 4; ++nt) {
    const int h = (hs << 8) + (wn << 6) + (nt << 4) + (l & 15);
    const float q = qv[b * 512 + h];
    const float wa = w_att[h];
#pragma unroll
    for (int mt = 0; mt < 2; ++mt)
#pragma unroll
      for (int r = 0; r < 4; ++r) {
        float x = q + acc[mt][nt][r];
        float e = __expf(x + x);
        float t = 1.f - __fdividef(2.f, e + 1.f);
        rs[mt * 4 + r] = __builtin_fmaf(t, wa, rs[mt * 4 + r]);
      }
  }
#pragma unroll
  for (int st = 1; st <= 8; st <<= 1)
#pragma unroll
    for (int i = 0; i < 8; ++i)
      rs[i] += __shfl_xor(rs[i], st, 64);

  {
    const int idx = l & 15;
    if (idx < 8) {
      float v = rs[0];
#pragma unroll
      for (int i = 1; i < 8; ++i) v = (idx == i) ? rs[i] : v;
      // local row: mt*16 + (l>>4)*4 + r
      const int rloc = ((idx >> 2) << 4) + ((l >> 4) << 2) + (idx & 3);
      sred[w * 32 + rloc] = v;
    }
  }
  __syncthreads();
  if (tid < 64) {
    const int wmq = tid >> 5, rl = tid & 31;
    float s = sred[(wmq * 4 + 0) * 32 + rl] + sred[(wmq * 4 + 1) * 32 + rl] +
              sred[(wmq * 4 + 2) * 32 + rl] + sred[(wmq * 4 + 3) * 32 + rl];
    spart_out[hs * 65536 + row0 + tid] = s;
  }
}

// ---------------- S: global softmax + attn + normalized V-partial ------------------
// Grid 1024 = (b, sc). Full-row scores = spart0 + spart1 -> exact softmax.
__global__ __launch_bounds__(256) void softv_kernel(
    const float* __restrict__ keys, const float* __restrict__ spart,
    float* __restrict__ attn, _Float16* __restrict__ vpart) {
  __shared__ float pe[2048];
  __shared__ float red_mx[4], red_se[4];
  __shared__ float4 comb[128];
  const int tid = threadIdx.x;
  const int b = blockIdx.x >> 5, sc = blockIdx.x & 31;
  const float* p0 = spart + (size_t)b * 2048;
  const float* p1 = spart + 65536 + (size_t)b * 2048;

  float sv[8];
  float mx = -1e30f;
#pragma unroll
  for (int i = 0; i < 8; ++i) {
    sv[i] = p0[i * 256 + tid] + p1[i * 256 + tid];
    mx = fmaxf(mx, sv[i]);
  }
#pragma unroll
  for (int st = 32; st >= 1; st >>= 1) mx = fmaxf(mx, __shfl_xor(mx, st, 64));
  if ((tid & 63) == 0) red_mx[tid >> 6] = mx;
  __syncthreads();
  mx = fmaxf(fmaxf(red_mx[0], red_mx[1]), fmaxf(red_mx[2], red_mx[3]));

  float se = 0.f;
#pragma unroll
  for (int i = 0; i < 8; ++i) {
    float e = __expf(sv[i] - mx);
    pe[i * 256 + tid] = e;
    se += e;
  }
#pragma unroll
  for (int st = 32; st >= 1; st >>= 1) se += __shfl_xor(se, st, 64);
  if ((tid & 63) == 0) red_se[tid >> 6] = se;
  __syncthreads();     // pe[] complete + red_se visible
  se = red_se[0] + red_se[1] + red_se[2] + red_se[3];
  const float rinv = 1.f / se;

  if (tid < 64) {
    int s = sc * 64 + tid;
    attn[(size_t)b * 2048 + s] = pe[s] * rinv;
  }

  // V: thread (c4, rg): float4 col c4, rows rg*32..+32 of this chunk
  const int c4 = tid & 127, rg = tid >> 7;
  const float4* kb = (const float4*)(keys + ((size_t)(b * 2048 + sc * 64 + rg * 32)) * 512);
  float4 a; a.x = 0.f; a.y = 0.f; a.z = 0.f; a.w = 0.f;
#pragma unroll 4
  for (int i = 0; i < 32; ++i) {
    float p = pe[sc * 64 + rg * 32 + i];
    float4 kv = kb[(size_t)i * 128 + c4];
    a.x = __builtin_fmaf(p, kv.x, a.x);
    a.y = __builtin_fmaf(p, kv.y, a.y);
    a.z = __builtin_fmaf(p, kv.z, a.z);
    a.w = __builtin_fmaf(p, kv.w, a.w);
  }
  if (rg) comb[c4] = a;
  __syncthreads();
  if (!rg) {
    float4 o = comb[c4];
    f16x4 h;
    h[0] = (_Float16)((a.x + o.x) * rinv);
    h[1] = (_Float16)((a.y + o.y) * rinv);
    h[2] = (_Float16)((a.z + o.z) * rinv);
    h[3] = (_Float16)((a.w + o.w) * rinv);
    *(f16x4*)(vpart + (size_t)blockIdx.x * 512 + c4 * 4) = h;
  }
}

// ---------------- R: reduce 32 chunk-partials -> out -------------------------------
__global__ __launch_bounds__(256) void reduce_kernel(
    const _Float16* __restrict__ vpart, float* __restrict__ out) {
  const int t = blockIdx.x * 256 + threadIdx.x;   // 16384 outputs
  const int b = t >> 9, d = t & 511;
  float s = 0.f;
#pragma unroll
  for (int sc = 0; sc < 32; ++sc)
    s += (float)vpart[((size_t)(b * 32 + sc)) * 512 + d];
  out[t] = s;
}

extern "C" void kernel_launch(void* const* d_in, const int* in_sizes, int n_in,
                              void* d_out, int out_size, void* d_ws, size_t ws_size,
                              hipStream_t stream) {
  const float* query = (const float*)d_in[0];
  const float* keys  = (const float*)d_in[1];
  const float* Wq    = (const float*)d_in[2];
  const float* Wk    = (const float*)d_in[3];
  const float* w_att = (const float*)d_in[4];
  float* out  = (float*)d_out;                  // [32,512]
  float* attn = out + 16384;                    // [32,2048]
  char* ws = (char*)d_ws;
  float*    qv     = (float*)(ws + WS_QV);
  _Float16* bfrag  = (_Float16*)(ws + WS_BF);
  float*    spart  = (float*)(ws + WS_SP);
  _Float16* vpart  = (_Float16*)(ws + WS_VP);

  prep_kernel<<<192, 256, 0, stream>>>(query, Wq, Wk, qv, bfrag);
  gemm_kernel<<<2048, 512, 0, stream>>>(keys, bfrag, qv, w_att, spart);
  softv_kernel<<<1024, 256, 0, stream>>>(keys, spart, attn, vpart);
  reduce_kernel<<<64, 256, 0, stream>>>(vpart, out);
}